// Round 12
// baseline (174.254 us; speedup 1.0000x reference)
//
#include <hip/hip_runtime.h>
#include <hip/hip_bf16.h>
#include <cstdint>

// LSTM cell: B=8192, D=1024, U=1024.
// z = [X|H](8192x2048) @ Wcat(2048x4096), gate interleave 16 in N, fused epilogue.
// GEMM: 256x128 tile, BK=32, 8 waves (4Mx2N), wave tile 64x64 (acc=64 VGPR),
// 3 LDS buffers x 24KB = 72KB -> 2 blocks/CU, 4 waves/SIMD (TLP fills stalls).
// Window: frag reads + stage-ahead-2 (3 GLL) + 16 MFMA + vmcnt(3) + barrier.

using f32x4  = __attribute__((ext_vector_type(4))) float;
using short8 = __attribute__((ext_vector_type(8))) short;

__device__ __forceinline__ unsigned short f2bf(float f) {
  union { float f; unsigned int u; } v; v.f = f;
  unsigned int r = v.u + 0x7fffu + ((v.u >> 16) & 1u);  // RNE
  return (unsigned short)(r >> 16);
}
__device__ __forceinline__ float sigmoidf_fast(float x) { return 1.f / (1.f + __expf(-x)); }
__device__ __forceinline__ float tanhf_fast(float x)    { return 1.f - 2.f / (__expf(2.f * x) + 1.f); }

// ---------- A conversion: Abf[b][k] = bf16(k<1024 ? X[b][k] : H[b][k-1024])
__global__ void conv_a_kernel(const float* __restrict__ X, const float* __restrict__ H,
                              unsigned short* __restrict__ Abf) {
  int idx = blockIdx.x * blockDim.x + threadIdx.x;
  int b  = idx >> 8;
  int kq = (idx & 255) << 2;
  float4 x = *(const float4*)(X + (long)b * 1024 + kq);
  float4 h = *(const float4*)(H + (long)b * 1024 + kq);
  ushort4 xo, ho;
  xo.x = f2bf(x.x); xo.y = f2bf(x.y); xo.z = f2bf(x.z); xo.w = f2bf(x.w);
  ho.x = f2bf(h.x); ho.y = f2bf(h.y); ho.z = f2bf(h.z); ho.w = f2bf(h.w);
  *(ushort4*)(Abf + (long)b * 2048 + kq)        = xo;
  *(ushort4*)(Abf + (long)b * 2048 + 1024 + kq) = ho;
}

// ---------- B conversion: Bt[n][k] bf16, N-major, n = (u>>4)*64 + g*16 + (u&15)
__global__ void conv_b_kernel(const float* W_i, const float* U_i,
                              const float* W_f, const float* U_f,
                              const float* W_c, const float* U_c,
                              const float* W_o, const float* U_o,
                              unsigned short* __restrict__ Bt) {
  __shared__ float tile[64][65];
  int z = blockIdx.z;
  const float* src;
  switch (z) {
    case 0: src = W_i; break; case 1: src = U_i; break;
    case 2: src = W_f; break; case 3: src = U_f; break;
    case 4: src = W_c; break; case 5: src = U_c; break;
    case 6: src = W_o; break; default: src = U_o; break;
  }
  int g = z >> 1, s = z & 1;
  int k0 = blockIdx.x * 64;
  int u0 = blockIdx.y * 64;
  int t = threadIdx.x;
  int c = t & 63, r0 = t >> 6;
#pragma unroll
  for (int i = 0; i < 16; ++i) {
    int r = i * 4 + r0;
    tile[r][c] = src[(long)(k0 + r) * 1024 + u0 + c];
  }
  __syncthreads();
  int ul = t >> 2;
  int ks = (t & 3) * 16;
  unsigned short outv[16];
#pragma unroll
  for (int j = 0; j < 16; ++j) outv[j] = f2bf(tile[ks + j][ul]);
  long n   = 4L * u0 + (ul >> 4) * 64 + g * 16 + (ul & 15);
  long col = (long)s * 1024 + k0 + ks;
  uint4* dst = (uint4*)(Bt + n * 2048 + col);
  dst[0] = *(uint4*)(outv);
  dst[1] = *(uint4*)(outv + 8);
}

// ---------- fused GEMM + LSTM epilogue
// LDS buffer (12288 shorts = 24KB): A[256][32] at +0, B[128][32] at +8192. 3 bufs.
__global__ __launch_bounds__(512, 4) void lstm_gemm_kernel(
    const unsigned short* __restrict__ Abf,   // [8192][2048] bf16
    const unsigned short* __restrict__ Btbf,  // [4096][2048] bf16 (N-major)
    const float* __restrict__ b_i, const float* __restrict__ b_f,
    const float* __restrict__ b_c, const float* __restrict__ b_o,
    const float* __restrict__ c_tm1,
    float* __restrict__ outH, float* __restrict__ outC) {
  __shared__ unsigned short smem[3 * 12288];  // 72KB

  int bid = blockIdx.x;
  int swz = (bid & 7) * 128 + (bid >> 3);  // XCD swizzle, 1024 % 8 == 0
  int bm = swz >> 5;   // 32 m-blocks (M=8192/256)
  int bn = swz & 31;   // 32 n-blocks (N=4096/128)

  int t = threadIdx.x;
  int lane = t & 63;
  int w = t >> 6;           // 8 waves
  int wm = w >> 1;          // 0..3
  int wn = w & 1;           // 0..1
  int rl = lane & 15;
  int kg = lane >> 4;       // 0..3, 8-elem k-chunk

  // ---- frag ds_read offsets within a buffer (XOR chunk swizzle c ^= (row>>1)&3) ----
#define AOFFE(MI) (((wm * 64 + (MI) * 16 + rl) * 32) + \
    ((kg ^ (((wm * 64 + (MI) * 16 + rl) >> 1) & 3)) << 3))
#define BOFFE(NI) (8192 + ((wn * 64 + (NI) * 16 + rl) * 32) + \
    ((kg ^ (((wn * 64 + (NI) * 16 + rl) >> 1) & 3)) << 3))
  const int offA0 = AOFFE(0), offA1 = AOFFE(1), offA2 = AOFFE(2), offA3 = AOFFE(3);
  const int offB0 = BOFFE(0), offB1 = BOFFE(1), offB2 = BOFFE(2), offB3 = BOFFE(3);
#undef AOFFE
#undef BOFFE

  // ---- staging: linear LDS dest, inverse-swizzled global source ----
  int srow = t >> 2;                                  // 0..127
  int cbe  = ((t & 3) ^ ((srow >> 1) & 3)) << 3;      // source k-chunk (involution)
  const unsigned short* aS0 = Abf  + (long)(bm * 256 + srow) * 2048 + cbe;
  const unsigned short* aS1 = aS0 + 128L * 2048;
  const unsigned short* bS0 = Btbf + (long)(bn * 128 + srow) * 2048 + cbe;
  const int dA = t * 8;

#define GLL(SRC, DELM)                                                                     \
  __builtin_amdgcn_global_load_lds((const __attribute__((address_space(1))) void*)(SRC),   \
      (__attribute__((address_space(3))) void*)(&smem[DELM]), 16, 0, 0)
  // stage one tile (3 GLLs) into buffer SB at source k-offset KOFF
#define STAGE(SB, KOFF)                                                        \
  do {                                                                         \
    GLL(aS0 + (KOFF), (SB) * 12288 + dA);                                      \
    GLL(aS1 + (KOFF), (SB) * 12288 + 4096 + dA);                               \
    GLL(bS0 + (KOFF), (SB) * 12288 + 8192 + dA);                               \
  } while (0)
#define VMC(N) asm volatile("s_waitcnt vmcnt(" #N ")" ::: "memory")

  f32x4 acc[4][4];
#pragma unroll
  for (int mi = 0; mi < 4; ++mi)
#pragma unroll
    for (int ni = 0; ni < 4; ++ni) acc[mi][ni] = (f32x4){0.f, 0.f, 0.f, 0.f};

  short8 aw0, aw1, aw2, aw3, bb0, bb1, bb2, bb3;

#define MF4(AF, MI)                                                                      \
  acc[MI][0] = __builtin_amdgcn_mfma_f32_16x16x32_bf16(AF, bb0, acc[MI][0], 0, 0, 0);    \
  acc[MI][1] = __builtin_amdgcn_mfma_f32_16x16x32_bf16(AF, bb1, acc[MI][1], 0, 0, 0);    \
  acc[MI][2] = __builtin_amdgcn_mfma_f32_16x16x32_bf16(AF, bb2, acc[MI][2], 0, 0, 0);    \
  acc[MI][3] = __builtin_amdgcn_mfma_f32_16x16x32_bf16(AF, bb3, acc[MI][3], 0, 0, 0);

// Window w: read buf RB (tile w); stage tile w+2 -> buf SB; 16 MFMA;
// counted vmcnt(3) (leaves tile w+2's 3 loads in flight) + barrier.
#define WINDOW(RB, SB, KOFF, DOSTAGE, VMN, DOBAR)                              \
  {                                                                            \
    const unsigned short* S_ = smem + (RB) * 12288;                            \
    bb0 = *(const short8*)(S_ + offB0);                                        \
    bb1 = *(const short8*)(S_ + offB1);                                        \
    bb2 = *(const short8*)(S_ + offB2);                                        \
    bb3 = *(const short8*)(S_ + offB3);                                        \
    aw0 = *(const short8*)(S_ + offA0);                                        \
    aw1 = *(const short8*)(S_ + offA1);                                        \
    aw2 = *(const short8*)(S_ + offA2);                                        \
    aw3 = *(const short8*)(S_ + offA3);                                        \
    if (DOSTAGE) STAGE(SB, KOFF);                                              \
    __builtin_amdgcn_s_setprio(1);                                             \
    MF4(aw0, 0) MF4(aw1, 1) MF4(aw2, 2) MF4(aw3, 3)                            \
    __builtin_amdgcn_s_setprio(0);                                             \
    if ((VMN) == 3) VMC(3);                                                    \
    if ((VMN) == 0) VMC(0);                                                    \
    if (DOBAR) __builtin_amdgcn_s_barrier();                                   \
  }

  // ---- prologue: stage tile 0 -> buf0, tile 1 -> buf1; drain tile 0 ----
  STAGE(0, 0);
  STAGE(1, 32);
  VMC(3);
  __builtin_amdgcn_s_barrier();
  aS0 += 64; aS1 += 64; bS0 += 64;   // source base -> tile 2

  // ---- windows 0..59 (stage tiles 2..61) ----
  for (int g = 0; g < 20; ++g) {
    WINDOW(0, 2, 0,  1, 3, 1);
    WINDOW(1, 0, 32, 1, 3, 1);
    WINDOW(2, 1, 64, 1, 3, 1);
    aS0 += 96; aS1 += 96; bS0 += 96;
  }
  // ---- tail: w60 stages t62, w61 stages t63, w62 drains, w63 pure ----
  WINDOW(0, 2, 0,  1, 3, 1);
  WINDOW(1, 0, 32, 1, 3, 1);
  WINDOW(2, 0, 0,  0, 0, 1);
  WINDOW(0, 0, 0,  0, -1, 0);
#undef WINDOW
#undef MF4
#undef VMC
#undef STAGE
#undef GLL

  // ---- fused LSTM epilogue ----
  // Wave N-span = 64 cols = one u-block: u = nbase/4 + rl; gate = ni.
  int mbase = bm * 256 + wm * 64;
  int nbase = bn * 128 + wn * 64;
  int u = (nbase >> 2) + rl;
  float bi_v = b_i[u], bf_v = b_f[u], bc_v = b_c[u], bo_v = b_o[u];
  int rquad = (lane >> 4) << 2;
#pragma unroll
  for (int mi = 0; mi < 4; ++mi) {
#pragma unroll
    for (int j = 0; j < 4; ++j) {
      int brow = mbase + mi * 16 + rquad + j;
      float zi = acc[mi][0][j] + bi_v;
      float zf = acc[mi][1][j] + bf_v;
      float zc = acc[mi][2][j] + bc_v;
      float zo = acc[mi][3][j] + bo_v;
      float ig = sigmoidf_fast(zi);
      float fg = sigmoidf_fast(zf);
      float cg = tanhf_fast(zc);
      float og = sigmoidf_fast(zo);
      float cp = c_tm1[(long)brow * 1024 + u];
      float cn = fg * cp + ig * cg;
      float hn = og * tanhf_fast(cn);
      outH[(long)brow * 1024 + u] = hn;
      outC[(long)brow * 1024 + u] = cn;
    }
  }
}

extern "C" void kernel_launch(void* const* d_in, const int* in_sizes, int n_in,
                              void* d_out, int out_size, void* d_ws, size_t ws_size,
                              hipStream_t stream) {
  (void)in_sizes; (void)n_in; (void)out_size; (void)ws_size;
  const float* X   = (const float*)d_in[0];
  const float* Hst = (const float*)d_in[1];
  const float* Cst = (const float*)d_in[2];
  const float* W_i = (const float*)d_in[3];
  const float* U_i = (const float*)d_in[4];
  const float* b_i = (const float*)d_in[5];
  const float* W_f = (const float*)d_in[6];
  const float* U_f = (const float*)d_in[7];
  const float* b_f = (const float*)d_in[8];
  const float* W_c = (const float*)d_in[9];
  const float* U_c = (const float*)d_in[10];
  const float* b_c = (const float*)d_in[11];
  const float* W_o = (const float*)d_in[12];
  const float* U_o = (const float*)d_in[13];
  const float* b_o = (const float*)d_in[14];

  unsigned short* Abf  = (unsigned short*)d_ws;                        // 32 MB
  unsigned short* Btbf = (unsigned short*)((char*)d_ws + 33554432);    // 16 MB

  float* outH = (float*)d_out;
  float* outC = outH + 8192L * 1024;

  conv_a_kernel<<<8192, 256, 0, stream>>>(X, Hst, Abf);
  conv_b_kernel<<<dim3(16, 16, 8), 256, 0, stream>>>(W_i, U_i, W_f, U_f, W_c, U_c, W_o, U_o, Btbf);
  lstm_gemm_kernel<<<1024, 512, 0, stream>>>(Abf, Btbf, b_i, b_f, b_c, b_o, Cst, outH, outC);
}

// Round 13
// 168.854 us; speedup vs baseline: 1.0320x; 1.0320x over previous
//
#include <hip/hip_runtime.h>
#include <hip/hip_bf16.h>
#include <cstdint>

// LSTM cell: B=8192, D=1024, U=1024.
// z = [X|H](8192x2048) @ Wcat(2048x4096), gate interleave 32 in N, fused epilogue.
// GEMM: 256x256 tile, BK=32, 8 waves (4Mx2N), wave tile 64x128 via 32x32x16 MFMA
// (2 M-frags x 4 N-frags, acc = 8 x f32x16). 3 LDS buffers x 32KB = 96KB.
// Single-barrier window + counted vmcnt(4) (R8 structure). XOR chunk swizzle.

using f32x16 = __attribute__((ext_vector_type(16))) float;
using short8 = __attribute__((ext_vector_type(8))) short;

__device__ __forceinline__ unsigned short f2bf(float f) {
  union { float f; unsigned int u; } v; v.f = f;
  unsigned int r = v.u + 0x7fffu + ((v.u >> 16) & 1u);  // RNE
  return (unsigned short)(r >> 16);
}
__device__ __forceinline__ float sigmoidf_fast(float x) { return 1.f / (1.f + __expf(-x)); }
__device__ __forceinline__ float tanhf_fast(float x)    { return 1.f - 2.f / (__expf(2.f * x) + 1.f); }

// ---------- A conversion: Abf[b][k] = bf16(k<1024 ? X[b][k] : H[b][k-1024])
__global__ void conv_a_kernel(const float* __restrict__ X, const float* __restrict__ H,
                              unsigned short* __restrict__ Abf) {
  int idx = blockIdx.x * blockDim.x + threadIdx.x;
  int b  = idx >> 8;
  int kq = (idx & 255) << 2;
  float4 x = *(const float4*)(X + (long)b * 1024 + kq);
  float4 h = *(const float4*)(H + (long)b * 1024 + kq);
  ushort4 xo, ho;
  xo.x = f2bf(x.x); xo.y = f2bf(x.y); xo.z = f2bf(x.z); xo.w = f2bf(x.w);
  ho.x = f2bf(h.x); ho.y = f2bf(h.y); ho.z = f2bf(h.z); ho.w = f2bf(h.w);
  *(ushort4*)(Abf + (long)b * 2048 + kq)        = xo;
  *(ushort4*)(Abf + (long)b * 2048 + 1024 + kq) = ho;
}

// ---------- B conversion: Bt[n][k] bf16, N-major, n = (u>>5)*128 + g*32 + (u&31)
__global__ void conv_b_kernel(const float* W_i, const float* U_i,
                              const float* W_f, const float* U_f,
                              const float* W_c, const float* U_c,
                              const float* W_o, const float* U_o,
                              unsigned short* __restrict__ Bt) {
  __shared__ float tile[64][65];
  int z = blockIdx.z;
  const float* src;
  switch (z) {
    case 0: src = W_i; break; case 1: src = U_i; break;
    case 2: src = W_f; break; case 3: src = U_f; break;
    case 4: src = W_c; break; case 5: src = U_c; break;
    case 6: src = W_o; break; default: src = U_o; break;
  }
  int g = z >> 1, s = z & 1;
  int k0 = blockIdx.x * 64;
  int u0 = blockIdx.y * 64;
  int t = threadIdx.x;
  int c = t & 63, r0 = t >> 6;
#pragma unroll
  for (int i = 0; i < 16; ++i) {
    int r = i * 4 + r0;
    tile[r][c] = src[(long)(k0 + r) * 1024 + u0 + c];
  }
  __syncthreads();
  int ul = t >> 2;
  int ks = (t & 3) * 16;
  unsigned short outv[16];
#pragma unroll
  for (int j = 0; j < 16; ++j) outv[j] = f2bf(tile[ks + j][ul]);
  long n   = 4L * u0 + (ul >> 5) * 128 + g * 32 + (ul & 31);
  long col = (long)s * 1024 + k0 + ks;
  uint4* dst = (uint4*)(Bt + n * 2048 + col);
  dst[0] = *(uint4*)(outv);
  dst[1] = *(uint4*)(outv + 8);
}

// ---------- fused GEMM + LSTM epilogue
// LDS buf (16384 shorts = 32KB): A[256][32] at +0, B[256][32] at +8192. 3 bufs.
__global__ __launch_bounds__(512, 2) void lstm_gemm_kernel(
    const unsigned short* __restrict__ Abf,   // [8192][2048] bf16
    const unsigned short* __restrict__ Btbf,  // [4096][2048] bf16 (N-major)
    const float* __restrict__ b_i, const float* __restrict__ b_f,
    const float* __restrict__ b_c, const float* __restrict__ b_o,
    const float* __restrict__ c_tm1,
    float* __restrict__ outH, float* __restrict__ outC) {
  __shared__ unsigned short smem[49152];  // 96KB

  int bid = blockIdx.x;
  int swz = (bid & 7) * 64 + (bid >> 3);  // XCD swizzle, 512 % 8 == 0
  int bm = swz >> 4;   // 32 m-blocks
  int bn = swz & 15;   // 16 n-blocks

  int t = threadIdx.x;
  int lane = t & 63;
  int w = t >> 6;           // 8 waves
  int wm = w >> 1;          // 0..3  (M quarter)
  int wn = w & 1;           // 0..1  (N half)
  int rl = lane & 31;       // row/col within 32-frag
  int kh = lane >> 5;       // 0..1, 8-elem k-group

  // ---- ds_read frag offsets (XOR chunk swizzle: chunk ^= (row>>1)&3) ----
  // A frag (MI,KK): row = wm*64 + MI*32 + rl, chunk = (kh + KK*2)
#define AOFFE(MI, KK) (((wm * 64 + (MI) * 32 + rl) * 32) + \
    ((((kh) + (KK) * 2) ^ (((wm * 64 + (MI) * 32 + rl) >> 1) & 3)) << 3))
  // B frag (NI,KK): n-row = wn*128 + NI*32 + rl, chunk = (kh + KK*2)
#define BOFFE(NI, KK) (8192 + ((wn * 128 + (NI) * 32 + rl) * 32) + \
    ((((kh) + (KK) * 2) ^ (((wn * 128 + (NI) * 32 + rl) >> 1) & 3)) << 3))
  const int offA00 = AOFFE(0, 0), offA10 = AOFFE(1, 0);
  const int offA01 = AOFFE(0, 1), offA11 = AOFFE(1, 1);
  const int offB00 = BOFFE(0, 0), offB10 = BOFFE(1, 0), offB20 = BOFFE(2, 0), offB30 = BOFFE(3, 0);
  const int offB01 = BOFFE(0, 1), offB11 = BOFFE(1, 1), offB21 = BOFFE(2, 1), offB31 = BOFFE(3, 1);
#undef AOFFE
#undef BOFFE

  // ---- staging: linear LDS dest, inverse-swizzled global source ----
  int srow = t >> 2;                                  // 0..127 (+128 second GLL)
  int cbe  = ((t & 3) ^ ((srow >> 1) & 3)) << 3;      // source k-chunk (involution)
  const unsigned short* aS0 = Abf  + (long)(bm * 256 + srow) * 2048 + cbe;
  const unsigned short* aS1 = aS0 + 128L * 2048;
  const unsigned short* bS0 = Btbf + (long)(bn * 256 + srow) * 2048 + cbe;
  const unsigned short* bS1 = bS0 + 128L * 2048;
  const int dA = t * 8;

#define GLL(SRC, DELM)                                                                     \
  __builtin_amdgcn_global_load_lds((const __attribute__((address_space(1))) void*)(SRC),   \
      (__attribute__((address_space(3))) void*)(&smem[DELM]), 16, 0, 0)
#define VMC(N) asm volatile("s_waitcnt vmcnt(" #N ")" ::: "memory")

  f32x16 acc[2][4];
#pragma unroll
  for (int mi = 0; mi < 2; ++mi)
#pragma unroll
    for (int ni = 0; ni < 4; ++ni)
#pragma unroll
      for (int j = 0; j < 16; ++j) acc[mi][ni][j] = 0.f;

  short8 a00, a10, a01, a11;             // A frags: (mi, kk)
  short8 b00, b10, b20, b30, b01, b11, b21, b31;  // B frags: (ni, kk)

#define MFMA32(A, B, C) __builtin_amdgcn_mfma_f32_32x32x16_bf16(A, B, C, 0, 0, 0)

// Window w: read buf RB (tile w); stage tile w+2 -> buf SB (4 GLL, split);
// 16 MFMA (kk0 cluster + kk1 cluster); counted vmcnt(4); barrier.
#define WINDOW(RB, SB, KOFF, DOSTAGE, VMN, DOBAR)                              \
  {                                                                            \
    const unsigned short* S_ = smem + (RB) * 16384;                            \
    b00 = *(const short8*)(S_ + offB00);                                       \
    b10 = *(const short8*)(S_ + offB10);                                       \
    b20 = *(const short8*)(S_ + offB20);                                       \
    b30 = *(const short8*)(S_ + offB30);                                       \
    a00 = *(const short8*)(S_ + offA00);                                       \
    a10 = *(const short8*)(S_ + offA10);                                       \
    if (DOSTAGE) {                                                             \
      GLL(aS0 + (KOFF), (SB) * 16384 + dA);                                    \
      GLL(aS1 + (KOFF), (SB) * 16384 + 4096 + dA);                             \
    }                                                                          \
    __builtin_amdgcn_s_setprio(1);                                             \
    acc[0][0] = MFMA32(a00, b00, acc[0][0]);                                   \
    acc[0][1] = MFMA32(a00, b10, acc[0][1]);                                   \
    acc[0][2] = MFMA32(a00, b20, acc[0][2]);                                   \
    acc[0][3] = MFMA32(a00, b30, acc[0][3]);                                   \
    acc[1][0] = MFMA32(a10, b00, acc[1][0]);                                   \
    acc[1][1] = MFMA32(a10, b10, acc[1][1]);                                   \
    acc[1][2] = MFMA32(a10, b20, acc[1][2]);                                   \
    acc[1][3] = MFMA32(a10, b30, acc[1][3]);                                   \
    __builtin_amdgcn_s_setprio(0);                                             \
    b01 = *(const short8*)(S_ + offB01);                                       \
    b11 = *(const short8*)(S_ + offB11);                                       \
    b21 = *(const short8*)(S_ + offB21);                                       \
    b31 = *(const short8*)(S_ + offB31);                                       \
    a01 = *(const short8*)(S_ + offA01);                                       \
    a11 = *(const short8*)(S_ + offA11);                                       \
    if (DOSTAGE) {                                                             \
      GLL(bS0 + (KOFF), (SB) * 16384 + 8192 + dA);                             \
      GLL(bS1 + (KOFF), (SB) * 16384 + 12288 + dA);                            \
    }                                                                          \
    __builtin_amdgcn_s_setprio(1);                                             \
    acc[0][0] = MFMA32(a01, b01, acc[0][0]);                                   \
    acc[0][1] = MFMA32(a01, b11, acc[0][1]);                                   \
    acc[0][2] = MFMA32(a01, b21, acc[0][2]);                                   \
    acc[0][3] = MFMA32(a01, b31, acc[0][3]);                                   \
    acc[1][0] = MFMA32(a11, b01, acc[1][0]);                                   \
    acc[1][1] = MFMA32(a11, b11, acc[1][1]);                                   \
    acc[1][2] = MFMA32(a11, b21, acc[1][2]);                                   \
    acc[1][3] = MFMA32(a11, b31, acc[1][3]);                                   \
    __builtin_amdgcn_s_setprio(0);                                             \
    if ((VMN) == 4) VMC(4);                                                    \
    if ((VMN) == 0) VMC(0);                                                    \
    if (DOBAR) __builtin_amdgcn_s_barrier();                                   \
  }

  // ---- prologue: stage tile 0 -> buf0, tile 1 -> buf1; drain tile 0 ----
  GLL(aS0, dA);            GLL(aS1, 4096 + dA);
  GLL(bS0, 8192 + dA);     GLL(bS1, 12288 + dA);
  GLL(aS0 + 32, 16384 + dA);        GLL(aS1 + 32, 16384 + 4096 + dA);
  GLL(bS0 + 32, 16384 + 8192 + dA); GLL(bS1 + 32, 16384 + 12288 + dA);
  VMC(4);
  __builtin_amdgcn_s_barrier();
  aS0 += 64; aS1 += 64; bS0 += 64; bS1 += 64;   // source base -> tile 2

  // ---- windows 0..59 (stage tiles 2..61) ----
  for (int g = 0; g < 20; ++g) {
    WINDOW(0, 2, 0,  1, 4, 1);
    WINDOW(1, 0, 32, 1, 4, 1);
    WINDOW(2, 1, 64, 1, 4, 1);
    aS0 += 96; aS1 += 96; bS0 += 96; bS1 += 96;
  }
  // ---- tail: w60 stages t62, w61 stages t63, w62 drains, w63 pure ----
  WINDOW(0, 2, 0,  1, 4, 1);
  WINDOW(1, 0, 32, 1, 4, 1);
  WINDOW(2, 0, 0,  0, 0, 1);
  WINDOW(0, 0, 0,  0, -1, 0);
#undef WINDOW
#undef MFMA32
#undef VMC
#undef GLL

  // ---- fused LSTM epilogue ----
  // 32x32 C/D layout: col = lane&31, row = (j&3) + 8*(j>>2) + 4*(lane>>5).
  // Wave N-span = 128 cols = 4 gate-frags: gate = ni, u = nbase/4 + (lane&31).
  int mbase = bm * 256 + wm * 64;
  int nbase = bn * 256 + wn * 128;
  int u = (nbase >> 2) + rl;
  float bi_v = b_i[u], bf_v = b_f[u], bc_v = b_c[u], bo_v = b_o[u];
#pragma unroll
  for (int mi = 0; mi < 2; ++mi) {
#pragma unroll
    for (int j = 0; j < 16; ++j) {
      int brow = mbase + mi * 32 + (j & 3) + 8 * (j >> 2) + 4 * kh;
      float zi = acc[mi][0][j] + bi_v;
      float zf = acc[mi][1][j] + bf_v;
      float zc = acc[mi][2][j] + bc_v;
      float zo = acc[mi][3][j] + bo_v;
      float ig = sigmoidf_fast(zi);
      float fg = sigmoidf_fast(zf);
      float cg = tanhf_fast(zc);
      float og = sigmoidf_fast(zo);
      float cp = c_tm1[(long)brow * 1024 + u];
      float cn = fg * cp + ig * cg;
      float hn = og * tanhf_fast(cn);
      outH[(long)brow * 1024 + u] = hn;
      outC[(long)brow * 1024 + u] = cn;
    }
  }
}

extern "C" void kernel_launch(void* const* d_in, const int* in_sizes, int n_in,
                              void* d_out, int out_size, void* d_ws, size_t ws_size,
                              hipStream_t stream) {
  (void)in_sizes; (void)n_in; (void)out_size; (void)ws_size;
  const float* X   = (const float*)d_in[0];
  const float* Hst = (const float*)d_in[1];
  const float* Cst = (const float*)d_in[2];
  const float* W_i = (const float*)d_in[3];
  const float* U_i = (const float*)d_in[4];
  const float* b_i = (const float*)d_in[5];
  const float* W_f = (const float*)d_in[6];
  const float* U_f = (const float*)d_in[7];
  const float* b_f = (const float*)d_in[8];
  const float* W_c = (const float*)d_in[9];
  const float* U_c = (const float*)d_in[10];
  const float* b_c = (const float*)d_in[11];
  const float* W_o = (const float*)d_in[12];
  const float* U_o = (const float*)d_in[13];
  const float* b_o = (const float*)d_in[14];

  unsigned short* Abf  = (unsigned short*)d_ws;                        // 32 MB
  unsigned short* Btbf = (unsigned short*)((char*)d_ws + 33554432);    // 16 MB

  float* outH = (float*)d_out;
  float* outC = outH + 8192L * 1024;

  conv_a_kernel<<<8192, 256, 0, stream>>>(X, Hst, Abf);
  conv_b_kernel<<<dim3(16, 16, 8), 256, 0, stream>>>(W_i, U_i, W_f, U_f, W_c, U_c, W_o, U_o, Btbf);
  lstm_gemm_kernel<<<512, 512, 0, stream>>>(Abf, Btbf, b_i, b_f, b_c, b_o, Cst, outH, outC);
}

// Round 14
// 161.692 us; speedup vs baseline: 1.0777x; 1.0443x over previous
//
#include <hip/hip_runtime.h>
#include <hip/hip_bf16.h>
#include <cstdint>

// LSTM cell: B=8192, D=1024, U=1024.
// z = [X|H](8192x2048) @ Wcat(2048x4096), gate interleave 16 in N, fused epilogue.
// GEMM: 256x256 tile, BK=32, 8 waves (4Mx2N), wave tile 64x128.
// A: fragment-major layout in workspace -> DIRECT coalesced global->VGPR loads
//    (1KB/frag, lane-contiguous), p/q double-buffered, 1 window ahead. No A LDS.
// B: LDS path, 3 bufs x 16KB, staged 2 ahead via global_load_lds, XOR swizzle.
// One explicit vmcnt(6) + one barrier per window.

using f32x4  = __attribute__((ext_vector_type(4))) float;
using short8 = __attribute__((ext_vector_type(8))) short;

__device__ __forceinline__ unsigned short f2bf(float f) {
  union { float f; unsigned int u; } v; v.f = f;
  unsigned int r = v.u + 0x7fffu + ((v.u >> 16) & 1u);  // RNE
  return (unsigned short)(r >> 16);
}
__device__ __forceinline__ float sigmoidf_fast(float x) { return 1.f / (1.f + __expf(-x)); }
__device__ __forceinline__ float tanhf_fast(float x)    { return 1.f - 2.f / (__expf(2.f * x) + 1.f); }

// ---------- A conversion: fragment-major A'.
// A'[(((bm*64 + kt)*16 + f)*64 + l)*8 + e] = bf16(src[bm*256 + f*16 + (l&15)]
//   [kt*32 + (l>>4)*8 + e]), src = X for kt<32 else H (k-1024).
__global__ void conv_a_kernel(const float* __restrict__ X, const float* __restrict__ H,
                              unsigned short* __restrict__ Ap) {
  __shared__ float tile[256][36];
  int kt = blockIdx.x;       // 0..63
  int bm = blockIdx.y;       // 0..31
  const float* src = (kt < 32) ? X : H;
  int kbase = (kt & 31) * 32;
  int t = threadIdx.x;
#pragma unroll
  for (int i = 0; i < 8; ++i) {
    int flat = i * 256 + t;          // 0..2047
    int row = flat >> 3;             // 0..255
    int kq  = (flat & 7) * 4;
    float4 v = *(const float4*)(src + (long)(bm * 256 + row) * 1024 + kbase + kq);
    tile[row][kq]     = v.x; tile[row][kq + 1] = v.y;
    tile[row][kq + 2] = v.z; tile[row][kq + 3] = v.w;
  }
  __syncthreads();
  long obase = (long)(bm * 64 + kt) * 8192;   // 16 frags * 512 elems
#pragma unroll
  for (int i = 0; i < 4; ++i) {
    int p = i * 256 + t;             // (f,l) pair, 0..1023
    int f = p >> 6, l = p & 63;
    int row = f * 16 + (l & 15);
    int kc  = (l >> 4) * 8;
    float4 v0 = *(const float4*)&tile[row][kc];
    float4 v1 = *(const float4*)&tile[row][kc + 4];
    unsigned short ov[8];
    ov[0] = f2bf(v0.x); ov[1] = f2bf(v0.y); ov[2] = f2bf(v0.z); ov[3] = f2bf(v0.w);
    ov[4] = f2bf(v1.x); ov[5] = f2bf(v1.y); ov[6] = f2bf(v1.z); ov[7] = f2bf(v1.w);
    *(uint4*)(Ap + obase + (long)p * 8) = *(uint4*)ov;
  }
}

// ---------- B conversion: Bt[n][k] bf16, N-major, n = (u>>4)*64 + g*16 + (u&15)
__global__ void conv_b_kernel(const float* W_i, const float* U_i,
                              const float* W_f, const float* U_f,
                              const float* W_c, const float* U_c,
                              const float* W_o, const float* U_o,
                              unsigned short* __restrict__ Bt) {
  __shared__ float tile[64][65];
  int z = blockIdx.z;
  const float* src;
  switch (z) {
    case 0: src = W_i; break; case 1: src = U_i; break;
    case 2: src = W_f; break; case 3: src = U_f; break;
    case 4: src = W_c; break; case 5: src = U_c; break;
    case 6: src = W_o; break; default: src = U_o; break;
  }
  int g = z >> 1, s = z & 1;
  int k0 = blockIdx.x * 64;
  int u0 = blockIdx.y * 64;
  int t = threadIdx.x;
  int c = t & 63, r0 = t >> 6;
#pragma unroll
  for (int i = 0; i < 16; ++i) {
    int r = i * 4 + r0;
    tile[r][c] = src[(long)(k0 + r) * 1024 + u0 + c];
  }
  __syncthreads();
  int ul = t >> 2;
  int ks = (t & 3) * 16;
  unsigned short outv[16];
#pragma unroll
  for (int j = 0; j < 16; ++j) outv[j] = f2bf(tile[ks + j][ul]);
  long n   = 4L * u0 + (ul >> 4) * 64 + g * 16 + (ul & 15);
  long col = (long)s * 1024 + k0 + ks;
  uint4* dst = (uint4*)(Bt + n * 2048 + col);
  dst[0] = *(uint4*)(outv);
  dst[1] = *(uint4*)(outv + 8);
}

// ---------- fused GEMM + LSTM epilogue
__global__ __launch_bounds__(512, 2) void lstm_gemm_kernel(
    const unsigned short* __restrict__ Ap,    // fragment-major A'
    const unsigned short* __restrict__ Btbf,  // [4096][2048] bf16 (N-major)
    const float* __restrict__ b_i, const float* __restrict__ b_f,
    const float* __restrict__ b_c, const float* __restrict__ b_o,
    const float* __restrict__ c_tm1,
    float* __restrict__ outH, float* __restrict__ outC) {
  __shared__ unsigned short smem[3 * 8192];   // 3 B-buffers x 16KB = 48KB

  int bid = blockIdx.x;
  int swz = (bid & 7) * 64 + (bid >> 3);  // XCD swizzle, 512 % 8 == 0
  int bm = swz >> 4;   // 32 m-blocks
  int bn = swz & 15;   // 16 n-blocks

  int t = threadIdx.x;
  int lane = t & 63;
  int w = t >> 6;           // 8 waves
  int wm = w >> 1;          // 0..3 (M quarter, 64 rows)
  int wn = w & 1;           // 0..1 (N half, 128 cols)
  int rl = lane & 15;
  int kg = lane >> 4;       // 0..3

  // ---- B ds_read frag offsets (XOR chunk swizzle: chunk ^= (row>>1)&3) ----
#define BOFFE(NI) (((wn * 128 + (NI) * 16 + rl) * 32) + \
    ((kg ^ (((wn * 128 + (NI) * 16 + rl) >> 1) & 3)) << 3))
  const int offB0 = BOFFE(0), offB1 = BOFFE(1), offB2 = BOFFE(2), offB3 = BOFFE(3);
  const int offB4 = BOFFE(4), offB5 = BOFFE(5), offB6 = BOFFE(6), offB7 = BOFFE(7);
#undef BOFFE

  // ---- A direct: frag (wm*4+mi) of window kt at gA + kt*8192 + mi*512 ----
  const unsigned short* gA = Ap + ((long)bm * 64 * 16 + wm * 4) * 512 + lane * 8;

  // ---- B staging: linear LDS dest, inverse-swizzled global source ----
  int srow = t >> 2;                                  // 0..127 (+128 second GLL)
  int cbe  = ((t & 3) ^ ((srow >> 1) & 3)) << 3;      // source chunk (involution)
  const unsigned short* bS0 = Btbf + (long)(bn * 256 + srow) * 2048 + cbe;
  const unsigned short* bS1 = bS0 + 128L * 2048;
  const int dB = t * 8;

#define GLL(SRC, DELM)                                                                     \
  __builtin_amdgcn_global_load_lds((const __attribute__((address_space(1))) void*)(SRC),   \
      (__attribute__((address_space(3))) void*)(&smem[DELM]), 16, 0, 0)
#define GLLB(SB, KOFF)                                                         \
  do {                                                                         \
    GLL(bS0 + (KOFF), (SB) * 8192 + dB);                                       \
    GLL(bS1 + (KOFF), (SB) * 8192 + 4096 + dB);                                \
  } while (0)
#define VMC(N) asm volatile("s_waitcnt vmcnt(" #N ")" ::: "memory")

  f32x4 acc[4][8];
#pragma unroll
  for (int mi = 0; mi < 4; ++mi)
#pragma unroll
    for (int ni = 0; ni < 8; ++ni) acc[mi][ni] = (f32x4){0.f, 0.f, 0.f, 0.f};

  short8 pa0, pa1, pa2, pa3;   // A frag sets (p: even windows, q: odd)
  short8 qa0, qa1, qa2, qa3;
  short8 bb0, bb1, bb2, bb3, bb4, bb5, bb6, bb7;

#define LOADA(S, KOFF)                                                         \
  do {                                                                         \
    S##a0 = *(const short8*)(gA + (KOFF));                                     \
    S##a1 = *(const short8*)(gA + (KOFF) + 512);                               \
    S##a2 = *(const short8*)(gA + (KOFF) + 1024);                              \
    S##a3 = *(const short8*)(gA + (KOFF) + 1536);                              \
  } while (0)

#define MF8(AF, MI)                                                                      \
  acc[MI][0] = __builtin_amdgcn_mfma_f32_16x16x32_bf16(AF, bb0, acc[MI][0], 0, 0, 0);    \
  acc[MI][1] = __builtin_amdgcn_mfma_f32_16x16x32_bf16(AF, bb1, acc[MI][1], 0, 0, 0);    \
  acc[MI][2] = __builtin_amdgcn_mfma_f32_16x16x32_bf16(AF, bb2, acc[MI][2], 0, 0, 0);    \
  acc[MI][3] = __builtin_amdgcn_mfma_f32_16x16x32_bf16(AF, bb3, acc[MI][3], 0, 0, 0);    \
  acc[MI][4] = __builtin_amdgcn_mfma_f32_16x16x32_bf16(AF, bb4, acc[MI][4], 0, 0, 0);    \
  acc[MI][5] = __builtin_amdgcn_mfma_f32_16x16x32_bf16(AF, bb5, acc[MI][5], 0, 0, 0);    \
  acc[MI][6] = __builtin_amdgcn_mfma_f32_16x16x32_bf16(AF, bb6, acc[MI][6], 0, 0, 0);    \
  acc[MI][7] = __builtin_amdgcn_mfma_f32_16x16x32_bf16(AF, bb7, acc[MI][7], 0, 0, 0);

// Window w: A frags of w in set C (loaded at w-1); load A(w+1) into N (KOA);
// read B(w) from buf RB; stage B(w+2) -> buf SB (KOB); 32 MFMA; vmcnt; barrier.
#define WINDOW(RB, SB, KOA, KOB, C, N, DOA, DOST, VMN, DOBAR)                  \
  {                                                                            \
    if (DOA) LOADA(N, KOA);                                                    \
    const unsigned short* S_ = smem + (RB) * 8192;                             \
    bb0 = *(const short8*)(S_ + offB0);                                        \
    bb1 = *(const short8*)(S_ + offB1);                                        \
    bb2 = *(const short8*)(S_ + offB2);                                        \
    bb3 = *(const short8*)(S_ + offB3);                                        \
    bb4 = *(const short8*)(S_ + offB4);                                        \
    bb5 = *(const short8*)(S_ + offB5);                                        \
    bb6 = *(const short8*)(S_ + offB6);                                        \
    bb7 = *(const short8*)(S_ + offB7);                                        \
    if (DOST) GLLB(SB, KOB);                                                   \
    __builtin_amdgcn_s_setprio(1);                                             \
    MF8(C##a0, 0) MF8(C##a1, 1) MF8(C##a2, 2) MF8(C##a3, 3)                    \
    __builtin_amdgcn_s_setprio(0);                                             \
    if ((VMN) == 6) VMC(6);                                                    \
    if ((VMN) == 4) VMC(4);                                                    \
    if ((VMN) == 0) VMC(0);                                                    \
    if (DOBAR) __builtin_amdgcn_s_barrier();                                   \
  }

  // ---- prologue: stage B0->buf0, B1->buf1; load A(0)->p; drain B0 ----
  GLLB(0, 0);
  GLLB(1, 32);
  LOADA(p, 0);
  VMC(6);
  __builtin_amdgcn_s_barrier();
  bS0 += 64; bS1 += 64;   // B source base -> tile 2

  // ---- windows 0..59: 10 groups of 6 (A-set period 2, buf period 3) ----
  for (int g = 0; g < 10; ++g) {
    WINDOW(0, 2, 8192,  0,   p, q, 1, 1, 6, 1);
    WINDOW(1, 0, 16384, 32,  q, p, 1, 1, 6, 1);
    WINDOW(2, 1, 24576, 64,  p, q, 1, 1, 6, 1);
    WINDOW(0, 2, 32768, 96,  q, p, 1, 1, 6, 1);
    WINDOW(1, 0, 40960, 128, p, q, 1, 1, 6, 1);
    WINDOW(2, 1, 49152, 160, q, p, 1, 1, 6, 1);
    gA += 49152; bS0 += 192; bS1 += 192;
  }
  // ---- tail: w60 (stage B62), w61 (stage B63), w62 (drain B63), w63 (pure) ----
  WINDOW(0, 2, 8192,  0,  p, q, 1, 1, 6, 1);
  WINDOW(1, 0, 16384, 32, q, p, 1, 1, 6, 1);
  WINDOW(2, 0, 24576, 0,  p, q, 1, 0, 4, 1);
  WINDOW(0, 0, 0,     0,  q, p, 0, 0, -1, 0);
#undef WINDOW
#undef MF8
#undef LOADA
#undef VMC
#undef GLLB
#undef GLL

  // ---- fused LSTM epilogue ----
  // Wave N-span = 128 cols = two u-16-blocks; gate = ni&3, ublock = ni>>2.
  // C/D layout: col = lane&15, row = (lane>>4)*4 + j.
  int mbase = bm * 256 + wm * 64;
  int nbase = bn * 256 + wn * 128;
  int ub = nbase >> 2;
  int u0 = ub + rl;
  int u1 = ub + 16 + rl;
  float bi0 = b_i[u0], bf0 = b_f[u0], bc0 = b_c[u0], bo0 = b_o[u0];
  float bi1 = b_i[u1], bf1 = b_f[u1], bc1 = b_c[u1], bo1 = b_o[u1];
  int rquad = kg << 2;
#pragma unroll
  for (int mi = 0; mi < 4; ++mi) {
#pragma unroll
    for (int j = 0; j < 4; ++j) {
      int brow = mbase + mi * 16 + rquad + j;
      {
        float zi = acc[mi][0][j] + bi0;
        float zf = acc[mi][1][j] + bf0;
        float zc = acc[mi][2][j] + bc0;
        float zo = acc[mi][3][j] + bo0;
        float ig = sigmoidf_fast(zi);
        float fg = sigmoidf_fast(zf);
        float cg = tanhf_fast(zc);
        float og = sigmoidf_fast(zo);
        float cp = c_tm1[(long)brow * 1024 + u0];
        float cn = fg * cp + ig * cg;
        float hn = og * tanhf_fast(cn);
        outH[(long)brow * 1024 + u0] = hn;
        outC[(long)brow * 1024 + u0] = cn;
      }
      {
        float zi = acc[mi][4][j] + bi1;
        float zf = acc[mi][5][j] + bf1;
        float zc = acc[mi][6][j] + bc1;
        float zo = acc[mi][7][j] + bo1;
        float ig = sigmoidf_fast(zi);
        float fg = sigmoidf_fast(zf);
        float cg = tanhf_fast(zc);
        float og = sigmoidf_fast(zo);
        float cp = c_tm1[(long)brow * 1024 + u1];
        float cn = fg * cp + ig * cg;
        float hn = og * tanhf_fast(cn);
        outH[(long)brow * 1024 + u1] = hn;
        outC[(long)brow * 1024 + u1] = cn;
      }
    }
  }
}

extern "C" void kernel_launch(void* const* d_in, const int* in_sizes, int n_in,
                              void* d_out, int out_size, void* d_ws, size_t ws_size,
                              hipStream_t stream) {
  (void)in_sizes; (void)n_in; (void)out_size; (void)ws_size;
  const float* X   = (const float*)d_in[0];
  const float* Hst = (const float*)d_in[1];
  const float* Cst = (const float*)d_in[2];
  const float* W_i = (const float*)d_in[3];
  const float* U_i = (const float*)d_in[4];
  const float* b_i = (const float*)d_in[5];
  const float* W_f = (const float*)d_in[6];
  const float* U_f = (const float*)d_in[7];
  const float* b_f = (const float*)d_in[8];
  const float* W_c = (const float*)d_in[9];
  const float* U_c = (const float*)d_in[10];
  const float* b_c = (const float*)d_in[11];
  const float* W_o = (const float*)d_in[12];
  const float* U_o = (const float*)d_in[13];
  const float* b_o = (const float*)d_in[14];

  unsigned short* Ap   = (unsigned short*)d_ws;                        // 32 MB, fragment-major
  unsigned short* Btbf = (unsigned short*)((char*)d_ws + 33554432);    // 16 MB

  float* outH = (float*)d_out;
  float* outC = outH + 8192L * 1024;

  conv_a_kernel<<<dim3(64, 32), 256, 0, stream>>>(X, Hst, Ap);
  conv_b_kernel<<<dim3(16, 16, 8), 256, 0, stream>>>(W_i, U_i, W_f, U_f, W_c, U_c, W_o, U_o, Btbf);
  lstm_gemm_kernel<<<512, 512, 0, stream>>>(Ap, Btbf, b_i, b_f, b_c, b_o, Cst, outH, outC);
}